// Round 1
// baseline (401.887 us; speedup 1.0000x reference)
//
#include <hip/hip_runtime.h>

#define BN 2048   // batch
#define TN 2048   // time
#define CC 64     // chunks per row
#define TCH (TN / CC)  // 32 steps per chunk

__device__ __forceinline__ float ex2(float x){ return __builtin_amdgcn_exp2f(x); }
__device__ __forceinline__ float lg2(float x){ return __builtin_amdgcn_logf(x); }
__device__ __forceinline__ float rcpf(float x){ return __builtin_amdgcn_rcpf(x); }

constexpr float kLog2e = 1.4426950408889634f;
constexpr float kLn2   = 0.6931471805599453f;

__device__ __forceinline__ float fast_tanh(float x){
    float ax = fabsf(x);
    float e  = ex2(ax * (-2.0f * kLog2e));     // exp(-2|x|)
    float t  = (1.0f - e) * rcpf(1.0f + e);
    return copysignf(t, x);
}

__device__ __forceinline__ float sel4(float v0, float v1, float v2, float v3, int idx){
    float r = (idx == 1) ? v1 : v0;
    r = (idx == 2) ? v2 : r;
    r = (idx == 3) ? v3 : r;
    return r;
}

// Evolve NCOL exp-space alpha columns through nsteps of the 4-state recurrence.
// P holds exp-space values (non-negative), lacc holds base-2 log offsets per column.
template <int NCOL>
__device__ __forceinline__ void chunk_loop(
    int b, int tstart, int nsteps,
    const float* __restrict__ feats, const float* __restrict__ bias,
    const int* __restrict__ tags,
    const float (&AL)[4][4], const float (&M)[4][4],
    const float (&wsv)[4], const float (&wwv)[4], const float (&wnv)[4],
    float bwc, float bnc,
    const float* sA, const float* sM,
    float (&P)[4][NCOL], float (&lacc)[NCOL], float& gold, int& prev)
{
    const float* bp = bias + (size_t)b * TN;
    const int*   tp = tags + (size_t)b * TN;
    for (int s = 0; s < nsteps; ++s) {
        const int t = tstart + s;
        const float bv = bp[t];
        const int tg = tp[t];
        const float* fp = feats + ((size_t)b * TN + t) * 6;
        const float2 fa = *(const float2*)fp;
        const float2 fb = *(const float2*)(fp + 2);
        const float fi0 = fa.x, fi1 = fa.y, fi2 = fb.x, fi3 = fb.y;

        // gates g[j] = w_out[j] * tanh(bv*w_shift[j] + bias_const)
        const bool hw = bv > 0.5f;
        const float bc = hw ? bwc : bnc;
        float g[4], gL[4];
        #pragma unroll
        for (int j = 0; j < 4; ++j) {
            float x = fmaf(bv, wsv[j], bc);
            g[j]  = (hw ? wwv[j] : wnv[j]) * fast_tanh(x);
            gL[j] = g[j] * kLog2e;
        }
        const float fiL0 = fi0 * kLog2e, fiL1 = fi1 * kLog2e;
        const float fiL2 = fi2 * kLog2e, fiL3 = fi3 * kLog2e;
        const float fiL[4] = { fiL0, fiL1, fiL2, fiL3 };

        float nP[4][NCOL];
        #pragma unroll
        for (int i = 0; i < 4; ++i) {
            #pragma unroll
            for (int j = 0; j < NCOL; ++j) { nP[i][j] = 0.0f; }
        }
        // E[i][k] = exp(f[i] + A[i][k] + g[k]*M[i][k]) shared across columns
        #pragma unroll
        for (int k = 0; k < 4; ++k) {
            float Ek[4];
            #pragma unroll
            for (int i = 0; i < 4; ++i) {
                Ek[i] = ex2(fmaf(gL[k], M[i][k], fiL[i] + AL[i][k]));
            }
            #pragma unroll
            for (int j = 0; j < NCOL; ++j) {
                const float pk = P[k][j];
                #pragma unroll
                for (int i = 0; i < 4; ++i) { nP[i][j] = fmaf(Ek[i], pk, nP[i][j]); }
            }
        }
        #pragma unroll
        for (int i = 0; i < 4; ++i) {
            #pragma unroll
            for (int j = 0; j < NCOL; ++j) { P[i][j] = nP[i][j]; }
        }

        // gold partial: trans[tg,prev] + g[prev]*Mmod[tg,prev] + feats[tg]
        const int idx = tg * 4 + prev;
        gold += sA[idx] + sel4(g[0], g[1], g[2], g[3], prev) * sM[idx]
              + sel4(fi0, fi1, fi2, fi3, tg);
        prev = tg;

        // exact power-of-two renorm every 4 steps
        if ((s & 3) == 3) {
            #pragma unroll
            for (int j = 0; j < NCOL; ++j) {
                float m = fmaxf(fmaxf(P[0][j], P[1][j]), fmaxf(P[2][j], P[3][j]));
                int ee = (int)((__float_as_uint(m) >> 23) & 255u) - 126;
                float sc = __uint_as_float((unsigned)(127 - ee) << 23);
                lacc[j] += (float)ee;
                #pragma unroll
                for (int i = 0; i < 4; ++i) { P[i][j] *= sc; }
            }
        }
    }
}

extern "C" __global__ void __launch_bounds__(256)
crf_phase1(const float* __restrict__ feats, const float* __restrict__ bias,
           const int* __restrict__ tags, const float* __restrict__ trans,
           const float* __restrict__ wsh, const float* __restrict__ bno,
           const float* __restrict__ bwi, const float* __restrict__ wwo,
           const float* __restrict__ wno, const float* __restrict__ mult,
           float* __restrict__ matE, float* __restrict__ colOff,
           float* __restrict__ goldP)
{
    const int tid = blockIdx.x * 256 + threadIdx.x;
    const int b = tid & (BN - 1);
    const int c = tid >> 11;   // chunk index; uniform per block (8 blocks per c)

    // LDS tables for dynamically-indexed gold lookups
    __shared__ float sA[16], sM[16];
    if (threadIdx.x < 16) {
        const int i = threadIdx.x >> 2, j = threadIdx.x & 3;
        sA[threadIdx.x] = trans[i * 6 + j];
        // Mmod = softmax(multiplier, axis=0), then diag = -1
        const float m0 = mult[j], m1 = mult[4 + j], m2 = mult[8 + j], m3 = mult[12 + j];
        const float mx = fmaxf(fmaxf(m0, m1), fmaxf(m2, m3));
        const float e0 = ex2((m0 - mx) * kLog2e), e1 = ex2((m1 - mx) * kLog2e);
        const float e2 = ex2((m2 - mx) * kLog2e), e3 = ex2((m3 - mx) * kLog2e);
        const float inv = rcpf(e0 + e1 + e2 + e3);
        const float ei = (i == 0) ? e0 : (i == 1) ? e1 : (i == 2) ? e2 : e3;
        sM[threadIdx.x] = (i == j) ? -1.0f : ei * inv;
    }
    __syncthreads();

    float AL[4][4], M[4][4];
    #pragma unroll
    for (int i = 0; i < 4; ++i) {
        #pragma unroll
        for (int j = 0; j < 4; ++j) {
            AL[i][j] = trans[i * 6 + j] * kLog2e;   // base-2 scaled transitions
            M[i][j]  = sM[i * 4 + j];
        }
    }
    float wsv[4], wwv[4], wnv[4];
    #pragma unroll
    for (int j = 0; j < 4; ++j) { wsv[j] = wsh[j]; wwv[j] = wwo[j]; wnv[j] = wno[j]; }
    const float bwc = bwi[0], bnc = bno[0];

    float gold = 0.0f;
    int prev;
    if (c == 0) {
        // closed-form t=0: alpha1[i] = f[0,i] + trans[i,4] (others underflow exactly)
        const float* fp = feats + (size_t)b * TN * 6;
        const float f0 = fp[0], f1 = fp[1], f2 = fp[2], f3 = fp[3];
        const float t04 = trans[4], t14 = trans[10], t24 = trans[16], t34 = trans[22];
        const float a0 = f0 + t04, a1 = f1 + t14, a2 = f2 + t24, a3 = f3 + t34;
        const float mx = fmaxf(fmaxf(a0, a1), fmaxf(a2, a3));
        float P[4][1];
        P[0][0] = ex2((a0 - mx) * kLog2e);
        P[1][0] = ex2((a1 - mx) * kLog2e);
        P[2][0] = ex2((a2 - mx) * kLog2e);
        P[3][0] = ex2((a3 - mx) * kLog2e);
        float lacc[1] = { mx * kLog2e };
        const int tg = tags[(size_t)b * TN];
        // gold t=0: t0=START=4 -> base=trans[tg,4], no extra, emit f[tg]
        gold = sel4(t04, t14, t24, t34, tg) + sel4(f0, f1, f2, f3, tg);
        prev = tg;
        chunk_loop<1>(b, 1, TCH - 1, feats, bias, tags, AL, M, wsv, wwv, wnv,
                      bwc, bnc, sA, sM, P, lacc, gold, prev);
        #pragma unroll
        for (int i = 0; i < 4; ++i) { matE[i * BN + b] = P[i][0]; }
        colOff[b] = lacc[0];
        goldP[b]  = gold;
    } else {
        float P[4][4], lacc[4];
        #pragma unroll
        for (int i = 0; i < 4; ++i) {
            #pragma unroll
            for (int j = 0; j < 4; ++j) { P[i][j] = (i == j) ? 1.0f : 0.0f; }
        }
        #pragma unroll
        for (int j = 0; j < 4; ++j) { lacc[j] = 0.0f; }
        prev = tags[(size_t)b * TN + c * TCH - 1];
        chunk_loop<4>(b, c * TCH, TCH, feats, bias, tags, AL, M, wsv, wwv, wnv,
                      bwc, bnc, sA, sM, P, lacc, gold, prev);
        #pragma unroll
        for (int i = 0; i < 4; ++i) {
            #pragma unroll
            for (int j = 0; j < 4; ++j) { matE[(c * 16 + i * 4 + j) * BN + b] = P[i][j]; }
        }
        #pragma unroll
        for (int j = 0; j < 4; ++j) { colOff[(c * 4 + j) * BN + b] = lacc[j]; }
        goldP[c * BN + b] = gold;
    }
}

// One wave per row: ordered XOR-butterfly reduction of the 64 chunk operators.
extern "C" __global__ void __launch_bounds__(256)
crf_phase2(const float* __restrict__ matE, const float* __restrict__ colOff,
           const float* __restrict__ goldP, const float* __restrict__ trans,
           const int* __restrict__ tags, float* __restrict__ out)
{
    const int gtid = blockIdx.x * 256 + threadIdx.x;
    const int b = gtid >> 6;
    const int lane = threadIdx.x & 63;

    float Pe[4][4], so[4];
    float gold = goldP[lane * BN + b];
    if (lane == 0) {
        // chunk 0 is a vector; lift to rank-1 matrix (every column = v)
        #pragma unroll
        for (int i = 0; i < 4; ++i) {
            const float v = matE[i * BN + b];
            #pragma unroll
            for (int j = 0; j < 4; ++j) { Pe[i][j] = v; }
        }
        const float s0 = colOff[b];
        #pragma unroll
        for (int j = 0; j < 4; ++j) { so[j] = s0; }
    } else {
        #pragma unroll
        for (int i = 0; i < 4; ++i) {
            #pragma unroll
            for (int j = 0; j < 4; ++j) { Pe[i][j] = matE[(lane * 16 + i * 4 + j) * BN + b]; }
        }
        #pragma unroll
        for (int j = 0; j < 4; ++j) { so[j] = colOff[(lane * 4 + j) * BN + b]; }
    }

    #pragma unroll
    for (int d = 1; d < 64; d <<= 1) {
        float oP[4][4], os[4];
        #pragma unroll
        for (int i = 0; i < 4; ++i) {
            #pragma unroll
            for (int j = 0; j < 4; ++j) { oP[i][j] = __shfl_xor(Pe[i][j], d, 64); }
        }
        #pragma unroll
        for (int j = 0; j < 4; ++j) { os[j] = __shfl_xor(so[j], d, 64); }
        const bool hi = (lane & d) != 0;
        // C = A∘B with A = later (higher-lane) chunk, B = earlier
        float Ae[4][4], Be[4][4], sa[4], sb[4];
        #pragma unroll
        for (int i = 0; i < 4; ++i) {
            #pragma unroll
            for (int j = 0; j < 4; ++j) {
                Ae[i][j] = hi ? Pe[i][j] : oP[i][j];
                Be[i][j] = hi ? oP[i][j] : Pe[i][j];
            }
        }
        #pragma unroll
        for (int j = 0; j < 4; ++j) {
            sa[j] = hi ? so[j] : os[j];
            sb[j] = hi ? os[j] : so[j];
        }
        const float maxA = fmaxf(fmaxf(sa[0], sa[1]), fmaxf(sa[2], sa[3]));
        float Ap[4][4];
        #pragma unroll
        for (int k = 0; k < 4; ++k) {
            const float wk = ex2(sa[k] - maxA);
            #pragma unroll
            for (int i = 0; i < 4; ++i) { Ap[i][k] = Ae[i][k] * wk; }
        }
        #pragma unroll
        for (int j = 0; j < 4; ++j) {
            float c0 = 0.0f, c1 = 0.0f, c2 = 0.0f, c3 = 0.0f;
            #pragma unroll
            for (int k = 0; k < 4; ++k) {
                const float bk = Be[k][j];
                c0 = fmaf(Ap[0][k], bk, c0);
                c1 = fmaf(Ap[1][k], bk, c1);
                c2 = fmaf(Ap[2][k], bk, c2);
                c3 = fmaf(Ap[3][k], bk, c3);
            }
            const float m = fmaxf(fmaxf(c0, c1), fmaxf(c2, c3));
            const int ee = (int)((__float_as_uint(m) >> 23) & 255u) - 126;
            const float sc = __uint_as_float((unsigned)(127 - ee) << 23);
            Pe[0][j] = c0 * sc; Pe[1][j] = c1 * sc; Pe[2][j] = c2 * sc; Pe[3][j] = c3 * sc;
            so[j] = sb[j] + maxA + (float)ee;
        }
    }

    #pragma unroll
    for (int d = 1; d < 64; d <<= 1) { gold += __shfl_xor(gold, d, 64); }

    if (lane == 0) {
        const float t50 = trans[30], t51 = trans[31], t52 = trans[32], t53 = trans[33];
        const float ssum = Pe[0][0] * ex2(t50 * kLog2e) + Pe[1][0] * ex2(t51 * kLog2e)
                         + Pe[2][0] * ex2(t52 * kLog2e) + Pe[3][0] * ex2(t53 * kLog2e);
        const float fwd = (so[0] + lg2(ssum)) * kLn2;
        const int lastT = tags[(size_t)b * TN + TN - 1];
        const float gfin = gold + sel4(t50, t51, t52, t53, lastT);
        out[b] = fwd - gfin;
    }
}

extern "C" void kernel_launch(void* const* d_in, const int* in_sizes, int n_in,
                              void* d_out, int out_size, void* d_ws, size_t ws_size,
                              hipStream_t stream)
{
    const float* feats = (const float*)d_in[0];
    const float* bias  = (const float*)d_in[1];
    const int*   tags  = (const int*)d_in[2];
    const float* trans = (const float*)d_in[3];
    const float* wsh   = (const float*)d_in[4];
    const float* bno   = (const float*)d_in[5];
    const float* bwi   = (const float*)d_in[6];
    const float* wwo   = (const float*)d_in[7];
    const float* wno   = (const float*)d_in[8];
    const float* mult  = (const float*)d_in[9];
    float* out = (float*)d_out;

    float* matE   = (float*)d_ws;                          // CC*16*BN floats (8 MB)
    float* colOff = matE + (size_t)CC * 16 * BN;           // CC*4*BN floats (2 MB)
    float* goldP  = colOff + (size_t)CC * 4 * BN;          // CC*BN floats (0.5 MB)

    crf_phase1<<<(CC * BN) / 256, 256, 0, stream>>>(
        feats, bias, tags, trans, wsh, bno, bwi, wwo, wno, mult,
        matE, colOff, goldP);
    crf_phase2<<<(BN * 64) / 256, 256, 0, stream>>>(
        matE, colOff, goldP, trans, tags, out);
}

// Round 2
// 218.844 us; speedup vs baseline: 1.8364x; 1.8364x over previous
//
#include <hip/hip_runtime.h>

#define BN 2048   // batch
#define TN 2048   // time
#define BATCH 8   // steps per register-batched load group
#define SLOT 24   // floats per (b,chunk) result slot (16 P + 4 off + 1 gold + 3 pad)

__device__ __forceinline__ float ex2(float x){ return __builtin_amdgcn_exp2f(x); }
__device__ __forceinline__ float lg2(float x){ return __builtin_amdgcn_logf(x); }
__device__ __forceinline__ float rcpf(float x){ return __builtin_amdgcn_rcpf(x); }

constexpr float kLog2e = 1.4426950408889634f;
constexpr float kLn2   = 0.6931471805599453f;

__device__ __forceinline__ float fast_tanh(float x){
    float ax = fabsf(x);
    float e  = ex2(ax * (-2.0f * kLog2e));     // exp(-2|x|)
    float t  = (1.0f - e) * rcpf(1.0f + e);
    return copysignf(t, x);
}

__device__ __forceinline__ float sel4(float v0, float v1, float v2, float v3, int idx){
    float r = (idx == 1) ? v1 : v0;
    r = (idx == 2) ? v2 : r;
    r = (idx == 3) ? v3 : r;
    return r;
}

// Evolve NCOL exp-space alpha columns through one chunk (TCH steps) with
// register-batched global loads (BATCH steps per trip, lines fully consumed
// back-to-back => no fetch amplification).
template <int NCOL, bool CHUNK0, int TCH>
__device__ __forceinline__ void run_chunk(
    int b, int c,
    const float* __restrict__ feats, const float* __restrict__ bias,
    const int* __restrict__ tags,
    const float (&AL)[4][4], const float (&M)[4][4],
    const float (&wsv)[4], const float (&wwv)[4], const float (&wnv)[4],
    float bwc, float bnc, const float* sA, const float* sM,
    const float (&tc4)[4],
    float (&P)[4][NCOL], float (&lacc)[NCOL], float& gold, int& prev)
{
    const int t0c = c * TCH;
    #pragma unroll 1
    for (int bt = 0; bt < TCH / BATCH; ++bt) {
        const int t0 = t0c + bt * BATCH;
        // ---- batched loads (contiguous, line-exact) ----
        float Fr[BATCH * 6];
        {
            const float4* fp4 = (const float4*)(feats + ((size_t)b * TN + t0) * 6);
            #pragma unroll
            for (int q = 0; q < BATCH * 6 / 4; ++q) {
                const float4 v = fp4[q];
                Fr[q*4+0] = v.x; Fr[q*4+1] = v.y; Fr[q*4+2] = v.z; Fr[q*4+3] = v.w;
            }
        }
        float Bv[BATCH];
        {
            const float4* bp4 = (const float4*)(bias + (size_t)b * TN + t0);
            #pragma unroll
            for (int q = 0; q < BATCH / 4; ++q) {
                const float4 v = bp4[q];
                Bv[q*4+0] = v.x; Bv[q*4+1] = v.y; Bv[q*4+2] = v.z; Bv[q*4+3] = v.w;
            }
        }
        int Tg[BATCH];
        {
            const int4* tp4 = (const int4*)(tags + (size_t)b * TN + t0);
            #pragma unroll
            for (int q = 0; q < BATCH / 4; ++q) {
                const int4 v = tp4[q];
                Tg[q*4+0] = v.x; Tg[q*4+1] = v.y; Tg[q*4+2] = v.z; Tg[q*4+3] = v.w;
            }
        }
        // ---- compute BATCH steps ----
        #pragma unroll
        for (int s = 0; s < BATCH; ++s) {
            const float fi0 = Fr[s*6+0], fi1 = Fr[s*6+1];
            const float fi2 = Fr[s*6+2], fi3 = Fr[s*6+3];
            if (CHUNK0 && bt == 0 && s == 0) {
                // closed-form t=0: alpha1[i] = f[0,i] + trans[i,START]
                const float a0 = fi0 + tc4[0], a1 = fi1 + tc4[1];
                const float a2 = fi2 + tc4[2], a3 = fi3 + tc4[3];
                const float mx = fmaxf(fmaxf(a0, a1), fmaxf(a2, a3));
                P[0][0] = ex2((a0 - mx) * kLog2e);
                P[1][0] = ex2((a1 - mx) * kLog2e);
                P[2][0] = ex2((a2 - mx) * kLog2e);
                P[3][0] = ex2((a3 - mx) * kLog2e);
                lacc[0] = mx * kLog2e;
                const int tg0 = Tg[0];
                gold = sel4(tc4[0], tc4[1], tc4[2], tc4[3], tg0)
                     + sel4(fi0, fi1, fi2, fi3, tg0);
                prev = tg0;
                continue;
            }
            const float bv = Bv[s];
            const int tg = Tg[s];
            const bool hw = bv > 0.5f;
            const float bc = hw ? bwc : bnc;
            float g[4], gL[4];
            #pragma unroll
            for (int j = 0; j < 4; ++j) {
                float x = fmaf(bv, wsv[j], bc);
                g[j]  = (hw ? wwv[j] : wnv[j]) * fast_tanh(x);
                gL[j] = g[j] * kLog2e;
            }
            const float fiL[4] = { fi0 * kLog2e, fi1 * kLog2e,
                                   fi2 * kLog2e, fi3 * kLog2e };
            float nP[4][NCOL];
            #pragma unroll
            for (int i = 0; i < 4; ++i)
                #pragma unroll
                for (int j = 0; j < NCOL; ++j) nP[i][j] = 0.0f;
            #pragma unroll
            for (int k = 0; k < 4; ++k) {
                float Ek[4];
                #pragma unroll
                for (int i = 0; i < 4; ++i)
                    Ek[i] = ex2(fmaf(gL[k], M[i][k], fiL[i] + AL[i][k]));
                #pragma unroll
                for (int j = 0; j < NCOL; ++j) {
                    const float pk = P[k][j];
                    #pragma unroll
                    for (int i = 0; i < 4; ++i) nP[i][j] = fmaf(Ek[i], pk, nP[i][j]);
                }
            }
            #pragma unroll
            for (int i = 0; i < 4; ++i)
                #pragma unroll
                for (int j = 0; j < NCOL; ++j) P[i][j] = nP[i][j];

            const int idx = tg * 4 + prev;
            gold += sA[idx] + sel4(g[0], g[1], g[2], g[3], prev) * sM[idx]
                  + sel4(fi0, fi1, fi2, fi3, tg);
            prev = tg;

            if ((s & 3) == 3) {     // exact pow2 renorm every 4 steps
                #pragma unroll
                for (int j = 0; j < NCOL; ++j) {
                    float m = fmaxf(fmaxf(P[0][j], P[1][j]), fmaxf(P[2][j], P[3][j]));
                    int ee = (int)((__float_as_uint(m) >> 23) & 255u) - 126;
                    float sc = __uint_as_float((unsigned)(127 - ee) << 23);
                    lacc[j] += (float)ee;
                    #pragma unroll
                    for (int i = 0; i < 4; ++i) P[i][j] *= sc;
                }
            }
        }
    }
}

template <int CCv>
__global__ void __launch_bounds__(256)
crf_phase1(const float* __restrict__ feats, const float* __restrict__ bias,
           const int* __restrict__ tags, const float* __restrict__ trans,
           const float* __restrict__ wsh, const float* __restrict__ bno,
           const float* __restrict__ bwi, const float* __restrict__ wwo,
           const float* __restrict__ wno, const float* __restrict__ mult,
           float* __restrict__ matAll)
{
    constexpr int TCHv = TN / CCv;
    const int tid = blockIdx.x * 256 + threadIdx.x;
    const int b = tid & (BN - 1);
    const int c = tid >> 11;        // uniform per block

    __shared__ float sA[16], sM[16];
    if (threadIdx.x < 16) {
        const int i = threadIdx.x >> 2, j = threadIdx.x & 3;
        sA[threadIdx.x] = trans[i * 6 + j];
        const float m0 = mult[j], m1 = mult[4 + j], m2 = mult[8 + j], m3 = mult[12 + j];
        const float mx = fmaxf(fmaxf(m0, m1), fmaxf(m2, m3));
        const float e0 = ex2((m0 - mx) * kLog2e), e1 = ex2((m1 - mx) * kLog2e);
        const float e2 = ex2((m2 - mx) * kLog2e), e3 = ex2((m3 - mx) * kLog2e);
        const float inv = rcpf(e0 + e1 + e2 + e3);
        const float ei = (i == 0) ? e0 : (i == 1) ? e1 : (i == 2) ? e2 : e3;
        sM[threadIdx.x] = (i == j) ? -1.0f : ei * inv;
    }
    __syncthreads();

    float AL[4][4], M[4][4];
    #pragma unroll
    for (int i = 0; i < 4; ++i)
        #pragma unroll
        for (int j = 0; j < 4; ++j) {
            AL[i][j] = trans[i * 6 + j] * kLog2e;
            M[i][j]  = sM[i * 4 + j];
        }
    float wsv[4], wwv[4], wnv[4];
    #pragma unroll
    for (int j = 0; j < 4; ++j) { wsv[j] = wsh[j]; wwv[j] = wwo[j]; wnv[j] = wno[j]; }
    const float bwc = bwi[0], bnc = bno[0];
    const float tc4[4] = { trans[4], trans[10], trans[16], trans[22] };

    float o[SLOT];
    float gold = 0.0f;
    int prev;
    if (c == 0) {
        float P[4][1], lacc[1];
        run_chunk<1, true, TCHv>(b, 0, feats, bias, tags, AL, M, wsv, wwv, wnv,
                                 bwc, bnc, sA, sM, tc4, P, lacc, gold, prev);
        #pragma unroll
        for (int i = 0; i < 4; ++i)
            #pragma unroll
            for (int j = 0; j < 4; ++j) o[i * 4 + j] = P[i][0];   // rank-1 lift
        #pragma unroll
        for (int j = 0; j < 4; ++j) o[16 + j] = lacc[0];
    } else {
        float P[4][4], lacc[4] = {0.f, 0.f, 0.f, 0.f};
        #pragma unroll
        for (int i = 0; i < 4; ++i)
            #pragma unroll
            for (int j = 0; j < 4; ++j) P[i][j] = (i == j) ? 1.0f : 0.0f;
        prev = tags[(size_t)b * TN + c * TCHv - 1];
        run_chunk<4, false, TCHv>(b, c, feats, bias, tags, AL, M, wsv, wwv, wnv,
                                  bwc, bnc, sA, sM, tc4, P, lacc, gold, prev);
        #pragma unroll
        for (int i = 0; i < 4; ++i)
            #pragma unroll
            for (int j = 0; j < 4; ++j) o[i * 4 + j] = P[i][j];
        #pragma unroll
        for (int j = 0; j < 4; ++j) o[16 + j] = lacc[j];
    }
    o[20] = gold; o[21] = 0.f; o[22] = 0.f; o[23] = 0.f;
    float4* s4 = (float4*)(matAll + ((size_t)b * CCv + c) * SLOT);
    #pragma unroll
    for (int q = 0; q < SLOT / 4; ++q)
        s4[q] = make_float4(o[4*q], o[4*q+1], o[4*q+2], o[4*q+3]);
}

// C = A∘B (A later, B earlier) in exp-space with per-column base-2 offsets.
__device__ __forceinline__ void compose4(
    const float (&Ae)[4][4], const float (&sa)[4],
    const float (&Be)[4][4], const float (&sb)[4],
    float (&Ce)[4][4], float (&sc)[4])
{
    const float maxA = fmaxf(fmaxf(sa[0], sa[1]), fmaxf(sa[2], sa[3]));
    float Ap[4][4];
    #pragma unroll
    for (int k = 0; k < 4; ++k) {
        const float wk = ex2(sa[k] - maxA);
        #pragma unroll
        for (int i = 0; i < 4; ++i) Ap[i][k] = Ae[i][k] * wk;
    }
    #pragma unroll
    for (int j = 0; j < 4; ++j) {
        float c0 = 0.f, c1 = 0.f, c2 = 0.f, c3 = 0.f;
        #pragma unroll
        for (int k = 0; k < 4; ++k) {
            const float bk = Be[k][j];
            c0 = fmaf(Ap[0][k], bk, c0);
            c1 = fmaf(Ap[1][k], bk, c1);
            c2 = fmaf(Ap[2][k], bk, c2);
            c3 = fmaf(Ap[3][k], bk, c3);
        }
        const float m = fmaxf(fmaxf(c0, c1), fmaxf(c2, c3));
        const int ee = (int)((__float_as_uint(m) >> 23) & 255u) - 126;
        const float scf = __uint_as_float((unsigned)(127 - ee) << 23);
        Ce[0][j] = c0 * scf; Ce[1][j] = c1 * scf;
        Ce[2][j] = c2 * scf; Ce[3][j] = c3 * scf;
        sc[j] = sb[j] + maxA + (float)ee;
    }
}

template <int CCv>
__global__ void __launch_bounds__(256)
crf_phase2(const float* __restrict__ matAll, const float* __restrict__ trans,
           const int* __restrict__ tags, float* __restrict__ out)
{
    constexpr int CPL = CCv / 64;   // chunks per lane
    const int gtid = blockIdx.x * 256 + threadIdx.x;
    const int b = gtid >> 6;
    const int lane = threadIdx.x & 63;

    const float4* base = (const float4*)(matAll + ((size_t)b * CCv + lane * CPL) * SLOT);
    float Pe[4][4], so[4], gold;
    {
        float A[SLOT];
        #pragma unroll
        for (int q = 0; q < SLOT / 4; ++q) {
            const float4 v = base[q];
            A[4*q] = v.x; A[4*q+1] = v.y; A[4*q+2] = v.z; A[4*q+3] = v.w;
        }
        #pragma unroll
        for (int i = 0; i < 4; ++i)
            #pragma unroll
            for (int j = 0; j < 4; ++j) Pe[i][j] = A[i * 4 + j];
        #pragma unroll
        for (int j = 0; j < 4; ++j) so[j] = A[16 + j];
        gold = A[20];
    }
    if constexpr (CPL == 2) {
        float A[SLOT];
        #pragma unroll
        for (int q = 0; q < SLOT / 4; ++q) {
            const float4 v = base[SLOT / 4 + q];
            A[4*q] = v.x; A[4*q+1] = v.y; A[4*q+2] = v.z; A[4*q+3] = v.w;
        }
        float Ae[4][4], sa[4];
        #pragma unroll
        for (int i = 0; i < 4; ++i)
            #pragma unroll
            for (int j = 0; j < 4; ++j) Ae[i][j] = A[i * 4 + j];
        #pragma unroll
        for (int j = 0; j < 4; ++j) sa[j] = A[16 + j];
        gold += A[20];
        float Ce[4][4], sc[4];
        compose4(Ae, sa, Pe, so, Ce, sc);     // A is the later chunk
        #pragma unroll
        for (int i = 0; i < 4; ++i)
            #pragma unroll
            for (int j = 0; j < 4; ++j) Pe[i][j] = Ce[i][j];
        #pragma unroll
        for (int j = 0; j < 4; ++j) so[j] = sc[j];
    }

    #pragma unroll
    for (int d = 1; d < 64; d <<= 1) {
        float oP[4][4], os[4];
        #pragma unroll
        for (int i = 0; i < 4; ++i)
            #pragma unroll
            for (int j = 0; j < 4; ++j) oP[i][j] = __shfl_xor(Pe[i][j], d, 64);
        #pragma unroll
        for (int j = 0; j < 4; ++j) os[j] = __shfl_xor(so[j], d, 64);
        const bool hi = (lane & d) != 0;
        float Ae[4][4], Be[4][4], sa[4], sb[4];
        #pragma unroll
        for (int i = 0; i < 4; ++i)
            #pragma unroll
            for (int j = 0; j < 4; ++j) {
                Ae[i][j] = hi ? Pe[i][j] : oP[i][j];
                Be[i][j] = hi ? oP[i][j] : Pe[i][j];
            }
        #pragma unroll
        for (int j = 0; j < 4; ++j) {
            sa[j] = hi ? so[j] : os[j];
            sb[j] = hi ? os[j] : so[j];
        }
        float Ce[4][4], sc[4];
        compose4(Ae, sa, Be, sb, Ce, sc);
        #pragma unroll
        for (int i = 0; i < 4; ++i)
            #pragma unroll
            for (int j = 0; j < 4; ++j) Pe[i][j] = Ce[i][j];
        #pragma unroll
        for (int j = 0; j < 4; ++j) so[j] = sc[j];
    }

    #pragma unroll
    for (int d = 1; d < 64; d <<= 1) gold += __shfl_xor(gold, d, 64);

    if (lane == 0) {
        const float t50 = trans[30], t51 = trans[31], t52 = trans[32], t53 = trans[33];
        const float ssum = Pe[0][0] * ex2(t50 * kLog2e) + Pe[1][0] * ex2(t51 * kLog2e)
                         + Pe[2][0] * ex2(t52 * kLog2e) + Pe[3][0] * ex2(t53 * kLog2e);
        const float fwd = (so[0] + lg2(ssum)) * kLn2;
        const int lastT = tags[(size_t)b * TN + TN - 1];
        const float gfin = gold + sel4(t50, t51, t52, t53, lastT);
        out[b] = fwd - gfin;
    }
}

extern "C" void kernel_launch(void* const* d_in, const int* in_sizes, int n_in,
                              void* d_out, int out_size, void* d_ws, size_t ws_size,
                              hipStream_t stream)
{
    const float* feats = (const float*)d_in[0];
    const float* bias  = (const float*)d_in[1];
    const int*   tags  = (const int*)d_in[2];
    const float* trans = (const float*)d_in[3];
    const float* wsh   = (const float*)d_in[4];
    const float* bno   = (const float*)d_in[5];
    const float* bwi   = (const float*)d_in[6];
    const float* wwo   = (const float*)d_in[7];
    const float* wno   = (const float*)d_in[8];
    const float* mult  = (const float*)d_in[9];
    float* out = (float*)d_out;
    float* matAll = (float*)d_ws;

    const size_t need128 = (size_t)BN * 128 * SLOT * sizeof(float);  // 25.2 MB
    if (ws_size >= need128) {
        crf_phase1<128><<<(128 * BN) / 256, 256, 0, stream>>>(
            feats, bias, tags, trans, wsh, bno, bwi, wwo, wno, mult, matAll);
        crf_phase2<128><<<(BN * 64) / 256, 256, 0, stream>>>(matAll, trans, tags, out);
    } else {
        crf_phase1<64><<<(64 * BN) / 256, 256, 0, stream>>>(
            feats, bias, tags, trans, wsh, bno, bwi, wwo, wno, mult, matAll);
        crf_phase2<64><<<(BN * 64) / 256, 256, 0, stream>>>(matAll, trans, tags, out);
    }
}